// Round 13
// baseline (1595.780 us; speedup 1.0000x reference)
//
#include <hip/hip_runtime.h>

// ---------------------------------------------------------------------------
// HyperFNS: Helmholtz Jacobi + FNS spectral correction, B=8, N=256, K=3.
// Transforms = MFMA complex GEMMs (bf16 split-precision, K-interleaved);
// B-side staged straight from fp32 (split in-staging, packT eliminated);
// A-pack fused into GEMM epilogue. Conv chain fused, ch-inner NAMED-SCALAR
// accumulators (R8: vv-cache VGPR blowup; R9: array+pragma -> scratch).
// ---------------------------------------------------------------------------

#define BB 8
#define NN 65536          // 256*256
#define MM 66049          // 257*257

constexpr double PI_D    = 3.14159265358979323846;
constexpr double OMEGA_D = 40.0 * PI_D;
constexpr double H_D     = 1.0 / 255.0;
constexpr float  OMEGA2F = (float)(OMEGA_D * OMEGA_D);
constexpr float  BCVF    = (float)(2.0 * H_D * OMEGA_D);
constexpr float  INVH2F  = 65025.0f;
constexpr float  C1F     = (float)(-4.0 / (514.0 * 514.0));
constexpr float  TP514   = (float)(2.0 * PI_D / 514.0);

typedef __attribute__((ext_vector_type(8))) short short8v;
typedef __attribute__((ext_vector_type(8))) unsigned short us8;
typedef __attribute__((ext_vector_type(4))) float f32x4;

// --------------------------- bf16 split helpers -----------------------------
__device__ inline unsigned short bfh(float x) {
    unsigned u = __float_as_uint(x);
    unsigned r = (u + 0x7FFFu + ((u >> 16) & 1u)) >> 16;
    return (unsigned short)r;
}
__device__ inline float bfh_f(unsigned short h) {
    return __uint_as_float(((unsigned)h) << 16);
}
__device__ inline void bsplit(float x, unsigned short& h, unsigned short& l) {
    h = bfh(x);
    l = bfh(x - bfh_f(h));
}

// --------------------------- init -------------------------------------------
__global__ void k_init(const float* __restrict__ kappa, float* __restrict__ kap2,
                       float* __restrict__ dinv, float* __restrict__ x0,
                       float* __restrict__ acc) {
    int t = blockIdx.x * 256 + threadIdx.x;
    if (t < BB * NN) {
        float k = kappa[t];
        float k2 = k * k;
        kap2[t] = k2;
        dinv[t] = 1.0f / (4.0f * INVH2F - OMEGA2F * k2);
        x0[2 * t] = 0.f; x0[2 * t + 1] = 0.f;
    }
    if (t < 16) acc[t] = 0.f;
}

// --------------------------- transform matrices (fp32) ----------------------
__global__ void k_mats(float* __restrict__ S, float* __restrict__ W) {
    int t = blockIdx.x * 256 + threadIdx.x;
    if (t >= 257 * 257) return;
    int i = t / 257, j = t % 257;
    if (j < 256) {
        int a = (i - 128) * (j + 1);
        int m = ((a % 514) + 514) % 514;
        S[i * 256 + j] = sinf(m * TP514);
    }
    if (i < 256) {
        int tt = (i * (j + 129)) % 514;
        float cc = cosf(tt * TP514), ss = sinf(tt * TP514);
        float sg = (i & 1) ? -1.f : 1.f;
        W[(i * 257 + j) * 2] = sg * cc;
        W[(i * 257 + j) * 2 + 1] = -sg * ss;
    }
}

// --------------------------- static bf16 packs (KP=576 for W side) ----------
__global__ void k_packstat(const float* __restrict__ S, const float* __restrict__ W,
        unsigned short* sA1h, unsigned short* sA1l,
        unsigned short* sA2h, unsigned short* sA2l,
        unsigned short* wA1h, unsigned short* wA1l,
        unsigned short* wA2h, unsigned short* wA2l,
        unsigned short* wBh,  unsigned short* wBl) {
    int t = blockIdx.x * 256 + threadIdx.x;
    if (t >= 256 * 576) return;
    int i = t / 576, c = t % 576;
    {
        unsigned short h1 = 0, l1 = 0, h2 = 0, l2 = 0, hb = 0, lb = 0;
        if (c < 514) {
            int u = c >> 1;
            float wr = W[(i * 257 + u) * 2];
            float wi = W[(i * 257 + u) * 2 + 1];
            if ((c & 1) == 0) {
                bsplit(wr, h1, l1); bsplit(wi, h2, l2); bsplit(wr, hb, lb);
            } else {
                bsplit(-wi, h1, l1); bsplit(wr, h2, l2); bsplit(wi, hb, lb);
            }
        }
        size_t o = (size_t)i * 576 + c;
        wA1h[o] = h1; wA1l[o] = l1;
        wA2h[o] = h2; wA2l[o] = l2;
        wBh[o] = hb;  wBl[o] = lb;
    }
    if (i < 129 && c < 512) {
        int m = c >> 1;
        float s = S[i * 256 + m];
        unsigned short hs, ls;
        bsplit(s, hs, ls);
        size_t o = (size_t)i * 512 + c;
        if ((c & 1) == 0) { sA1h[o] = hs; sA1l[o] = ls; sA2h[o] = 0; sA2l[o] = 0; }
        else              { sA1h[o] = 0;  sA1l[o] = 0;  sA2h[o] = hs; sA2l[o] = ls; }
    }
}

// --------------------------- fused final residual + norm reduction ----------
__global__ void k_stepR(const float* __restrict__ xin,
                        const float* __restrict__ fr, const float* __restrict__ fi,
                        const float* __restrict__ kap2, float* __restrict__ acc) {
    int t = blockIdx.x * 256 + threadIdx.x;
    int b = t >> 16;
    int ij = t & 65535;
    int i = ij >> 8, j = ij & 255;
    const float* xb = xin + (size_t)b * NN * 2;
    float xcr = xb[2 * ij], xci = xb[2 * ij + 1];
    float ur, ui, dr, di, lr, li, rr, ri;
    if (i > 0) { int n = ij - 256; ur = xb[2 * n]; ui = xb[2 * n + 1]; }
    else { int n = 256 + j; ur = xb[2 * n] - BCVF * xci; ui = xb[2 * n + 1] + BCVF * xcr; }
    if (i < 255) { int n = ij + 256; dr = xb[2 * n]; di = xb[2 * n + 1]; }
    else { int n = 254 * 256 + j; dr = xb[2 * n] - BCVF * xci; di = xb[2 * n + 1] + BCVF * xcr; }
    if (j > 0) { int n = ij - 1; lr = xb[2 * n]; li = xb[2 * n + 1]; }
    else { int n = i * 256 + 1; lr = xb[2 * n] - BCVF * xci; li = xb[2 * n + 1] + BCVF * xcr; }
    if (j < 255) { int n = ij + 1; rr = xb[2 * n]; ri = xb[2 * n + 1]; }
    else { int n = i * 256 + 254; rr = xb[2 * n] - BCVF * xci; ri = xb[2 * n + 1] + BCVF * xcr; }
    float k2 = kap2[t];
    float axr = (4.f * xcr - ur - dr - lr - rr) * INVH2F - OMEGA2F * k2 * xcr;
    float axi = (4.f * xci - ui - di - li - ri) * INVH2F - OMEGA2F * k2 * xci;
    float fvr = fr[t], fvi = fi[t];
    float resr = fvr - axr, resi = fvi - axi;
    float sr = resr * resr + resi * resi;
    float sf = fvr * fvr + fvi * fvi;
    for (int off = 32; off > 0; off >>= 1) {
        sr += __shfl_down(sr, off);
        sf += __shfl_down(sf, off);
    }
    __shared__ float ssr[4], ssf[4];
    int tid = threadIdx.x;
    int wid = tid >> 6, lane = tid & 63;
    if (lane == 0) { ssr[wid] = sr; ssf[wid] = sf; }
    __syncthreads();
    if (tid == 0) {
        atomicAdd(&acc[2 * b], ssr[0] + ssr[1] + ssr[2] + ssr[3]);
        atomicAdd(&acc[2 * b + 1], ssf[0] + ssf[1] + ssf[2] + ssf[3]);
    }
}

// --------------------------- fused double stencil ---------------------------
template<int RESID>
__global__ __launch_bounds__(256) void k_step2(
        const float* __restrict__ xin, float* __restrict__ xout, float* __restrict__ rb,
        const float* __restrict__ fr, const float* __restrict__ fi,
        const float* __restrict__ kap2, const float* __restrict__ dinv) {
    const int b = blockIdx.y;
    const int tx = blockIdx.x & 7, ty = blockIdx.x >> 3;
    const int x0 = tx * 32, y0 = ty * 8;
    __shared__ float2 xs[12][37];
    __shared__ float2 ys[10][35];
    __shared__ float2 fs[10][35];
    __shared__ float ks2[10][35], ds2[10][35];
    const int tid = threadIdx.x;
    const float2* xb = (const float2*)xin + (size_t)b * NN;
    for (int i = tid; i < 432; i += 256) {
        int r = i / 36, c = i % 36;
        int gy = y0 - 2 + r, gx = x0 - 2 + c;
        float2 v = make_float2(0.f, 0.f);
        if ((unsigned)gy < 256u && (unsigned)gx < 256u) v = xb[gy * 256 + gx];
        xs[r][c] = v;
    }
    for (int i = tid; i < 340; i += 256) {
        int r = i / 34, c = i % 34;
        int gy = y0 - 1 + r, gx = x0 - 1 + c;
        float2 fv = make_float2(0.f, 0.f); float kv = 0.f, dvv = 0.f;
        if ((unsigned)gy < 256u && (unsigned)gx < 256u) {
            size_t o = (size_t)b * NN + gy * 256 + gx;
            fv = make_float2(fr[o], fi[o]); kv = kap2[o]; dvv = dinv[o];
        }
        fs[r][c] = fv; ks2[r][c] = kv; ds2[r][c] = dvv;
    }
    __syncthreads();
    for (int i = tid; i < 340; i += 256) {
        int r = i / 34, c = i % 34;
        int gy = y0 - 1 + r, gx = x0 - 1 + c;
        float2 o = make_float2(0.f, 0.f);
        if ((unsigned)gy < 256u && (unsigned)gx < 256u) {
            int xr = r + 1, xc = c + 1;
            float2 ctr = xs[xr][xc];
            float2 up, dn, lf, rt;
            if (gy > 0) up = xs[xr - 1][xc];
            else { float2 n = xs[xr + 1][xc]; up = make_float2(n.x - BCVF * ctr.y, n.y + BCVF * ctr.x); }
            if (gy < 255) dn = xs[xr + 1][xc];
            else { float2 n = xs[xr - 1][xc]; dn = make_float2(n.x - BCVF * ctr.y, n.y + BCVF * ctr.x); }
            if (gx > 0) lf = xs[xr][xc - 1];
            else { float2 n = xs[xr][xc + 1]; lf = make_float2(n.x - BCVF * ctr.y, n.y + BCVF * ctr.x); }
            if (gx < 255) rt = xs[xr][xc + 1];
            else { float2 n = xs[xr][xc - 1]; rt = make_float2(n.x - BCVF * ctr.y, n.y + BCVF * ctr.x); }
            float k2 = ks2[r][c];
            float axr = (4.f * ctr.x - up.x - dn.x - lf.x - rt.x) * INVH2F - OMEGA2F * k2 * ctr.x;
            float axi = (4.f * ctr.y - up.y - dn.y - lf.y - rt.y) * INVH2F - OMEGA2F * k2 * ctr.y;
            float2 fv = fs[r][c];
            float dv = ds2[r][c] * (2.0f / 3.0f);
            o = make_float2(ctr.x + dv * (fv.x - axr), ctr.y + dv * (fv.y - axi));
        }
        ys[r][c] = o;
    }
    __syncthreads();
    const int lx = tid & 31, ly = tid >> 5;
    const int gy = y0 + ly, gx = x0 + lx;
    const int yr = ly + 1, yc = lx + 1;
    float2 ctr = ys[yr][yc];
    float2 up, dn, lf, rt;
    if (gy > 0) up = ys[yr - 1][yc];
    else { float2 n = ys[yr + 1][yc]; up = make_float2(n.x - BCVF * ctr.y, n.y + BCVF * ctr.x); }
    if (gy < 255) dn = ys[yr + 1][yc];
    else { float2 n = ys[yr - 1][yc]; dn = make_float2(n.x - BCVF * ctr.y, n.y + BCVF * ctr.x); }
    if (gx > 0) lf = ys[yr][yc - 1];
    else { float2 n = ys[yr][yc + 1]; lf = make_float2(n.x - BCVF * ctr.y, n.y + BCVF * ctr.x); }
    if (gx < 255) rt = ys[yr][yc + 1];
    else { float2 n = ys[yr][yc - 1]; rt = make_float2(n.x - BCVF * ctr.y, n.y + BCVF * ctr.x); }
    float k2 = ks2[yr][yc];
    float axr = (4.f * ctr.x - up.x - dn.x - lf.x - rt.x) * INVH2F - OMEGA2F * k2 * ctr.x;
    float axi = (4.f * ctr.y - up.y - dn.y - lf.y - rt.y) * INVH2F - OMEGA2F * k2 * ctr.y;
    float2 fv = fs[yr][yc];
    size_t t = (size_t)b * NN + gy * 256 + gx;
    if (!RESID) {
        float dv = ds2[yr][yc] * (2.0f / 3.0f);
        xout[2 * t] = ctr.x + dv * (fv.x - axr);
        xout[2 * t + 1] = ctr.y + dv * (fv.y - axi);
    } else {
        xout[2 * t] = ctr.x; xout[2 * t + 1] = ctr.y;
        rb[2 * t] = fv.x - axr; rb[2 * t + 1] = fv.y - axi;
    }
}

// --------------------------- MFMA complex GEMM ------------------------------
// EPI: 0 store C, 1 add into C, 2 mirror-store (odd sym 257x257, scale),
//      3 write next-GEMM A-pack (P1/P2 h,l) instead of C.
// BGLO: stage B straight from fp32 cplx global (split in staging; no packT).
template<int EPI, int BGLO>
__global__ __launch_bounds__(256) void mgemm(
        const unsigned short* __restrict__ A1h, const unsigned short* __restrict__ A1l,
        const unsigned short* __restrict__ A2h, const unsigned short* __restrict__ A2l,
        const unsigned short* __restrict__ Bh,  const unsigned short* __restrict__ Bl,
        const float* __restrict__ Bgf, int ldbf, long bStrG, int bMin,
        float* __restrict__ C,
        unsigned short* __restrict__ P1h, unsigned short* __restrict__ P1l,
        unsigned short* __restrict__ P2h, unsigned short* __restrict__ P2l,
        int M, int N, int KP, int ldc, int KPout,
        long aStr, long bStr, long cStrF2, long pStr, float scale) {
    constexpr int LR = 72;
    __shared__ unsigned short shA1h[32 * LR], shA1l[32 * LR];
    __shared__ unsigned short shA2h[32 * LR], shA2l[32 * LR];
    __shared__ unsigned short shBh[32 * LR], shBl[32 * LR];
    const int tid = threadIdx.x;
    const int b = blockIdx.z;
    const unsigned short* pA1h = A1h + (size_t)b * aStr;
    const unsigned short* pA1l = A1l + (size_t)b * aStr;
    const unsigned short* pA2h = A2h + (size_t)b * aStr;
    const unsigned short* pA2l = A2l + (size_t)b * aStr;
    const int m0 = blockIdx.y * 32, n0 = blockIdx.x * 32;
    const int wave = tid >> 6, lane = tid & 63;
    const int wm = wave >> 1, wn = wave & 1;
    const int srow = tid >> 3, scol = (tid & 7) * 8;

    f32x4 accr = {0.f, 0.f, 0.f, 0.f}, acci = {0.f, 0.f, 0.f, 0.f};
    const int nks = KP >> 6;
    for (int ks = 0; ks < nks; ks++) {
        const int kb = ks * 64;
        const int so = srow * LR + scol;
        {
            int gm = m0 + srow;
            if (gm < M) {
                size_t ao = (size_t)gm * KP + kb + scol;
                *(us8*)&shA1h[so] = *(const us8*)&pA1h[ao];
                *(us8*)&shA1l[so] = *(const us8*)&pA1l[ao];
                *(us8*)&shA2h[so] = *(const us8*)&pA2h[ao];
                *(us8*)&shA2l[so] = *(const us8*)&pA2l[ao];
            } else {
                us8 z = (us8)0;
                *(us8*)&shA1h[so] = z; *(us8*)&shA1l[so] = z;
                *(us8*)&shA2h[so] = z; *(us8*)&shA2l[so] = z;
            }
        }
        if (BGLO) {
            // B[k'=2u+e][n] from fp32 cplx Bgf[u][n], staged n-major:
            // shB[n_local * LR + k'_local], k' = 2*ul (+1 for imag).
            int ul = tid >> 3;            // 0..31 local u (k' pair)
            int nl = (tid & 7) * 4;       // 0..28 local n
            int gu = (kb >> 1) + ul;
            const float2* bp = (const float2*)Bgf + (size_t)b * bStrG
                               + (size_t)gu * ldbf + (n0 + nl);
#pragma unroll
            for (int j = 0; j < 4; j++) {
                float2 v = make_float2(0.f, 0.f);
                if (gu < bMin && (n0 + nl + j) < N) v = bp[j];
                unsigned short h0, l0, h1, l1;
                bsplit(v.x, h0, l0); bsplit(v.y, h1, l1);
                int o = (nl + j) * LR + 2 * ul;
                shBh[o] = h0;     shBl[o] = l0;
                shBh[o + 1] = h1; shBl[o + 1] = l1;
            }
        } else {
            const unsigned short* pBh = Bh + (size_t)b * bStr;
            const unsigned short* pBl = Bl + (size_t)b * bStr;
            int gn = n0 + srow;
            if (gn < N) {
                size_t bo = (size_t)gn * KP + kb + scol;
                *(us8*)&shBh[so] = *(const us8*)&pBh[bo];
                *(us8*)&shBl[so] = *(const us8*)&pBl[bo];
            } else {
                us8 z = (us8)0;
                *(us8*)&shBh[so] = z; *(us8*)&shBl[so] = z;
            }
        }
        __syncthreads();
#pragma unroll
        for (int half = 0; half < 2; half++) {
            const int ko = half * 32 + ((lane >> 4) << 3);
            const int ar = (wm * 16 + (lane & 15)) * LR + ko;
            const int br = (wn * 16 + (lane & 15)) * LR + ko;
            short8v a1h = *(const short8v*)&shA1h[ar];
            short8v a1l = *(const short8v*)&shA1l[ar];
            short8v a2h = *(const short8v*)&shA2h[ar];
            short8v a2l = *(const short8v*)&shA2l[ar];
            short8v bh  = *(const short8v*)&shBh[br];
            short8v bl  = *(const short8v*)&shBl[br];
            accr = __builtin_amdgcn_mfma_f32_16x16x32_bf16(a1h, bh, accr, 0, 0, 0);
            accr = __builtin_amdgcn_mfma_f32_16x16x32_bf16(a1l, bh, accr, 0, 0, 0);
            accr = __builtin_amdgcn_mfma_f32_16x16x32_bf16(a1h, bl, accr, 0, 0, 0);
            acci = __builtin_amdgcn_mfma_f32_16x16x32_bf16(a2h, bh, acci, 0, 0, 0);
            acci = __builtin_amdgcn_mfma_f32_16x16x32_bf16(a2l, bh, acci, 0, 0, 0);
            acci = __builtin_amdgcn_mfma_f32_16x16x32_bf16(a2h, bl, acci, 0, 0, 0);
        }
        __syncthreads();
    }
    const int col = n0 + wn * 16 + (lane & 15);
    const int rbase = m0 + wm * 16 + ((lane >> 4) << 2);
    if (EPI == 3) {
        unsigned short* q1h = P1h + (size_t)b * pStr;
        unsigned short* q1l = P1l + (size_t)b * pStr;
        unsigned short* q2h = P2h + (size_t)b * pStr;
        unsigned short* q2l = P2l + (size_t)b * pStr;
#pragma unroll
        for (int i = 0; i < 4; i++) {
            int row = rbase + i;
            if (row >= M || col >= N) continue;
            float vr = scale * accr[i], vi = scale * acci[i];
            unsigned short hr, lr2, hi2, li2;
            bsplit(vr, hr, lr2); bsplit(vi, hi2, li2);
            size_t o = (size_t)row * KPout + 2 * col;
            q1h[o] = hr;  q1h[o + 1] = hi2 ^ 0x8000;
            q1l[o] = lr2; q1l[o + 1] = li2 ^ 0x8000;
            q2h[o] = hi2; q2h[o + 1] = hr;
            q2l[o] = li2; q2l[o + 1] = lr2;
        }
    } else {
        float* Cb = C + (size_t)b * cStrF2 * 2;
#pragma unroll
        for (int i = 0; i < 4; i++) {
            int row = rbase + i;
            if (row >= M || col >= N) continue;
            float vr = scale * accr[i], vi = scale * acci[i];
            if (EPI == 2) {
                int mm = 256 - row, nm = 256 - col;
                Cb[((size_t)row * 257 + col) * 2] = vr;  Cb[((size_t)row * 257 + col) * 2 + 1] = vi;
                Cb[((size_t)mm * 257 + col) * 2] = -vr;  Cb[((size_t)mm * 257 + col) * 2 + 1] = -vi;
                Cb[((size_t)row * 257 + nm) * 2] = -vr;  Cb[((size_t)row * 257 + nm) * 2 + 1] = -vi;
                Cb[((size_t)mm * 257 + nm) * 2] = vr;    Cb[((size_t)mm * 257 + nm) * 2 + 1] = vi;
            } else {
                size_t o = ((size_t)row * ldc + col) * 2;
                if (EPI == 1) { Cb[o] += vr; Cb[o + 1] += vi; }
                else          { Cb[o] = vr;  Cb[o + 1] = vi; }
            }
        }
    }
}

// --------------------------- fused 3-conv chain (+wt), ch-inner scalars -----
// ADJ=0: w1(1->4), w2(4->4), w3(4->1), then *wt (WTM).
// ADJ=1: w3^H(1->4), w2^H(4->4), w1^H(4->1).
#define CACC(AR, AI, W) { AR += v.x * (W).x - v.y * (W).y; AI += v.x * (W).y + v.y * (W).x; }
template<int ADJ, int WTM>
__global__ __launch_bounds__(256) void k_convChain(
        const float* __restrict__ in, float* __restrict__ out,
        const float* __restrict__ w1r, const float* __restrict__ w1i,
        const float* __restrict__ w2r, const float* __restrict__ w2i,
        const float* __restrict__ w3r, const float* __restrict__ w3i,
        const float* __restrict__ wtr, const float* __restrict__ wti) {
    const int b = blockIdx.y;
    const int bx = blockIdx.x % 9, by = blockIdx.x / 9;
    const int x0 = bx * 32, y0 = by * 8;
    __shared__ float2 sh0[14][39];
    __shared__ float2 i1[4][12][37];
    __shared__ float2 i2[4][10][35];
    __shared__ float2 wA2[36], wB2[144], wC2[36];
    const int tid = threadIdx.x;
    if (tid < 36) {
        int o = tid / 9, pq = tid % 9, p = pq / 3, q = pq % 3;
        if (!ADJ) { int idx = b * 36 + o * 9 + pq; wA2[tid] = make_float2(w1r[idx], w1i[idx]); }
        else      { int idx = b * 36 + o * 9 + q * 3 + p; wA2[tid] = make_float2(w3r[idx], -w3i[idx]); }
    } else if (tid < 180) {
        int j = tid - 36; int o = j / 36, ci = (j / 9) & 3, pq = j % 9, p = pq / 3, q = pq % 3;
        if (!ADJ) { int idx = b * 144 + (o * 4 + ci) * 9 + pq; wB2[j] = make_float2(w2r[idx], w2i[idx]); }
        else      { int idx = b * 144 + (ci * 4 + o) * 9 + q * 3 + p; wB2[j] = make_float2(w2r[idx], -w2i[idx]); }
    } else if (tid < 216) {
        int j = tid - 180; int ci = j / 9, pq = j % 9, p = pq / 3, q = pq % 3;
        if (!ADJ) { int idx = b * 36 + ci * 9 + pq; wC2[j] = make_float2(w3r[idx], w3i[idx]); }
        else      { int idx = b * 36 + ci * 9 + q * 3 + p; wC2[j] = make_float2(w1r[idx], -w1i[idx]); }
    }
    const float2* ipb = (const float2*)in + (size_t)b * MM;
    for (int i = tid; i < 14 * 38; i += 256) {
        int r = i / 38, c = i % 38;
        int gy = y0 - 3 + r, gx = x0 - 3 + c;
        float2 v = make_float2(0.f, 0.f);
        if ((unsigned)gy < 257u && (unsigned)gx < 257u) v = ipb[(size_t)gy * 257 + gx];
        sh0[r][c] = v;
    }
    __syncthreads();
    // pass 1 (1->4): 9 data + 36 w LDS reads, named scalar accumulators.
    for (int pos = tid; pos < 432; pos += 256) {
        int r = pos / 36, c = pos % 36;
        int gy = y0 - 2 + r, gx = x0 - 2 + c;
        bool ok = ((unsigned)gy < 257u) & ((unsigned)gx < 257u);
        float ar0 = 0.f, ai0 = 0.f, ar1 = 0.f, ai1 = 0.f;
        float ar2 = 0.f, ai2 = 0.f, ar3 = 0.f, ai3 = 0.f;
#pragma unroll
        for (int p = 0; p < 3; p++)
#pragma unroll
            for (int q = 0; q < 3; q++) {
                float2 v = sh0[r + p][c + q];
                int k = p * 3 + q;
                CACC(ar0, ai0, wA2[k])
                CACC(ar1, ai1, wA2[9 + k])
                CACC(ar2, ai2, wA2[18 + k])
                CACC(ar3, ai3, wA2[27 + k])
            }
        float z = ok ? 1.f : 0.f;
        i1[0][r][c] = make_float2(z * ar0, z * ai0);
        i1[1][r][c] = make_float2(z * ar1, z * ai1);
        i1[2][r][c] = make_float2(z * ar2, z * ai2);
        i1[3][r][c] = make_float2(z * ar3, z * ai3);
    }
    __syncthreads();
    // pass 2 (4->4): 36 data + 144 w LDS reads, named scalar accumulators.
    for (int pos = tid; pos < 340; pos += 256) {
        int r = pos / 34, c = pos % 34;
        int gy = y0 - 1 + r, gx = x0 - 1 + c;
        bool ok = ((unsigned)gy < 257u) & ((unsigned)gx < 257u);
        float ar0 = 0.f, ai0 = 0.f, ar1 = 0.f, ai1 = 0.f;
        float ar2 = 0.f, ai2 = 0.f, ar3 = 0.f, ai3 = 0.f;
#pragma unroll
        for (int ci = 0; ci < 4; ci++)
#pragma unroll
            for (int p = 0; p < 3; p++)
#pragma unroll
                for (int q = 0; q < 3; q++) {
                    float2 v = i1[ci][r + p][c + q];
                    int k = ci * 9 + p * 3 + q;
                    CACC(ar0, ai0, wB2[k])
                    CACC(ar1, ai1, wB2[36 + k])
                    CACC(ar2, ai2, wB2[72 + k])
                    CACC(ar3, ai3, wB2[108 + k])
                }
        float z = ok ? 1.f : 0.f;
        i2[0][r][c] = make_float2(z * ar0, z * ai0);
        i2[1][r][c] = make_float2(z * ar1, z * ai1);
        i2[2][r][c] = make_float2(z * ar2, z * ai2);
        i2[3][r][c] = make_float2(z * ar3, z * ai3);
    }
    __syncthreads();
    // pass 3 (4->1)
    const int lx = tid & 31, ly = tid >> 5;
    const int x = x0 + lx, y = y0 + ly;
    if (x >= 257 || y >= 257) return;
    float ar = 0.f, ai = 0.f;
#pragma unroll
    for (int ci = 0; ci < 4; ci++)
#pragma unroll
        for (int p = 0; p < 3; p++)
#pragma unroll
            for (int q = 0; q < 3; q++) {
                float2 v = i2[ci][ly + p][lx + q];
                float2 w = wC2[ci * 9 + p * 3 + q];
                ar += v.x * w.x - v.y * w.y;
                ai += v.x * w.y + v.y * w.x;
            }
    if (WTM) {
        size_t wo = (size_t)b * MM + (size_t)y * 257 + x;
        float wr = wtr[wo], wi = wti[wo];
        float r0 = ar * wr - ai * wi;
        float i0 = ar * wi + ai * wr;
        ar = r0; ai = i0;
    }
    ((float2*)out)[(size_t)b * MM + (size_t)y * 257 + x] = make_float2(ar, ai);
}

__global__ void k_finalize(const float* __restrict__ acc, float* __restrict__ out) {
    if (threadIdx.x == 0 && blockIdx.x == 0) {
        float num = 0.f, den = 0.f;
        for (int b = 0; b < BB; b++) {
            num += sqrtf(acc[2 * b]);
            den += sqrtf(acc[2 * b + 1]);
        }
        out[0] = num / den;
    }
}

// ---------------------------------------------------------------------------
extern "C" void kernel_launch(void* const* d_in, const int* in_sizes, int n_in,
                              void* d_out, int out_size, void* d_ws, size_t ws_size,
                              hipStream_t stream) {
    (void)in_sizes; (void)n_in; (void)out_size; (void)ws_size;
    const float* fr  = (const float*)d_in[0];
    const float* fi  = (const float*)d_in[1];
    const float* kap = (const float*)d_in[2];
    const float* w1r = (const float*)d_in[3];
    const float* w1i = (const float*)d_in[4];
    const float* w2r = (const float*)d_in[5];
    const float* w2i = (const float*)d_in[6];
    const float* w3r = (const float*)d_in[7];
    const float* w3i = (const float*)d_in[8];
    const float* wtr = (const float*)d_in[9];
    const float* wti = (const float*)d_in[10];
    const int K = 3;   // epoch=81 -> (81-1)/40+1

    float* ws = (float*)d_ws;
    size_t off = 0;
    float* x0   = ws + off; off += (size_t)BB * NN * 2;
    float* x1   = ws + off; off += (size_t)BB * NN * 2;
    float* x2   = ws + off; off += (size_t)BB * NN * 2;
    float* rb   = ws + off; off += (size_t)BB * NN * 2;
    float* kap2 = ws + off; off += (size_t)BB * NN;
    float* dinv = ws + off; off += (size_t)BB * NN;
    float* tA   = ws + off; off += (size_t)BB * MM * 2;
    float* tB   = ws + off; off += (size_t)BB * MM * 2;
    float* u1   = ws + off; off += (size_t)BB * MM * 2;
    float* S    = ws + off; off += 257 * 256;
    float* W    = ws + off; off += 256 * 257 * 2;
    float* acc  = ws + off; off += 16;

    unsigned short* us = (unsigned short*)(ws + off);
    size_t so = 0;
    unsigned short* sA1h = us + so; so += 129 * 512;
    unsigned short* sA1l = us + so; so += 129 * 512;
    unsigned short* sA2h = us + so; so += 129 * 512;
    unsigned short* sA2l = us + so; so += 129 * 512;
    unsigned short* wA1h = us + so; so += 256 * 576;
    unsigned short* wA1l = us + so; so += 256 * 576;
    unsigned short* wA2h = us + so; so += 256 * 576;
    unsigned short* wA2l = us + so; so += 256 * 576;
    unsigned short* wBh  = us + so; so += 256 * 576;
    unsigned short* wBl  = us + so; so += 256 * 576;
    const long DSASTR = (long)129 * 512;
    unsigned short* dsA1h = us + so; so += (size_t)BB * DSASTR;
    unsigned short* dsA1l = us + so; so += (size_t)BB * DSASTR;
    unsigned short* dsA2h = us + so; so += (size_t)BB * DSASTR;
    unsigned short* dsA2l = us + so; so += (size_t)BB * DSASTR;
    const long DFASTR = (long)256 * 576;
    unsigned short* dfA1h = us + so; so += (size_t)BB * DFASTR;
    unsigned short* dfA1l = us + so; so += (size_t)BB * DFASTR;
    unsigned short* dfA2h = us + so; so += (size_t)BB * DFASTR;
    unsigned short* dfA2l = us + so; so += (size_t)BB * DFASTR;

    int sgrid = (BB * NN + 255) / 256;
    k_init<<<sgrid, 256, 0, stream>>>(kap, kap2, dinv, x0, acc);
    k_mats<<<(257 * 257 + 255) / 256, 256, 0, stream>>>(S, W);
    k_packstat<<<(256 * 576 + 255) / 256, 256, 0, stream>>>(
        S, W, sA1h, sA1l, sA2h, sA2l, wA1h, wA1l, wA2h, wA2l, wBh, wBl);

    float* xc = x0;
    for (int it = 0; it < K; ++it) {
        float* xn = (xc == x0) ? x2 : x0;
        k_step2<0><<<dim3(256, BB), 256, 0, stream>>>(xc, x1, rb, fr, fi, kap2, dinv);
        k_step2<1><<<dim3(256, BB), 256, 0, stream>>>(x1, xn, rb, fr, fi, kap2, dinv);

        // DST1: T[u<129][p<256] = S * rb  (B = rb fp32 direct) -> dsA pack
        mgemm<3, 1><<<dim3(8, 5, BB), 256, 0, stream>>>(
            sA1h, sA1l, sA2h, sA2l, nullptr, nullptr,
            rb, 256, (long)NN, 256,
            nullptr, dsA1h, dsA1l, dsA2h, dsA2l,
            129, 256, 512, 0, 512,
            0, 0, 0, DSASTR, 1.f);
        // DST2 quadrant + mirror -> tB (257x257)
        mgemm<2, 0><<<dim3(5, 5, BB), 256, 0, stream>>>(
            dsA1h, dsA1l, dsA2h, dsA2l, sA1h, sA1l,
            nullptr, 0, 0, 0,
            tB, nullptr, nullptr, nullptr, nullptr,
            129, 129, 512, 257, 0,
            DSASTR, 0, (long)MM, 0, C1F);

        // conv chains (forward +wt, adjoint)
        k_convChain<0, 1><<<dim3(297, BB), 256, 0, stream>>>(
            tB, u1, w1r, w1i, w2r, w2i, w3r, w3i, wtr, wti);
        k_convChain<1, 0><<<dim3(297, BB), 256, 0, stream>>>(
            u1, tA, w1r, w1i, w2r, w2i, w3r, w3i, wtr, wti);

        // DFT1: G[k<256][v<257] = W * tA  (B = tA fp32 direct) -> dfA pack
        mgemm<3, 1><<<dim3(9, 8, BB), 256, 0, stream>>>(
            wA1h, wA1l, wA2h, wA2l, nullptr, nullptr,
            tA, 257, (long)MM, 257,
            nullptr, dfA1h, dfA1l, dfA2h, dfA2l,
            256, 257, 576, 0, 576,
            0, 0, 0, DFASTR, 1.f);
        // DFT2 + add into xn
        mgemm<1, 0><<<dim3(8, 8, BB), 256, 0, stream>>>(
            dfA1h, dfA1l, dfA2h, dfA2l, wBh, wBl,
            nullptr, 0, 0, 0,
            xn, nullptr, nullptr, nullptr, nullptr,
            256, 256, 576, 256, 0,
            DFASTR, 0, (long)NN, 0, 1.f);
        xc = xn;
    }
    k_stepR<<<sgrid, 256, 0, stream>>>(xc, fr, fi, kap2, acc);
    k_finalize<<<1, 64, 0, stream>>>(acc, (float*)d_out);
}

// Round 14
// 596.517 us; speedup vs baseline: 2.6752x; 2.6752x over previous
//
#include <hip/hip_runtime.h>

// ---------------------------------------------------------------------------
// HyperFNS: Helmholtz Jacobi + FNS spectral correction, B=8, N=256, K=3.
// Transforms = MFMA complex GEMMs (bf16 split-precision, K-interleaved);
// B-side staged straight from fp32 (BGLO, packT eliminated); A-pack fused
// into GEMM epilogue. Conv chain = R7 channel-major body (44 VGPR; all
// ch-inner/position-major rewrites spill: R8 256VGPR, R9 scratch, R13 256VGPR).
// ---------------------------------------------------------------------------

#define BB 8
#define NN 65536          // 256*256
#define MM 66049          // 257*257

constexpr double PI_D    = 3.14159265358979323846;
constexpr double OMEGA_D = 40.0 * PI_D;
constexpr double H_D     = 1.0 / 255.0;
constexpr float  OMEGA2F = (float)(OMEGA_D * OMEGA_D);
constexpr float  BCVF    = (float)(2.0 * H_D * OMEGA_D);
constexpr float  INVH2F  = 65025.0f;
constexpr float  C1F     = (float)(-4.0 / (514.0 * 514.0));
constexpr float  TP514   = (float)(2.0 * PI_D / 514.0);

typedef __attribute__((ext_vector_type(8))) short short8v;
typedef __attribute__((ext_vector_type(8))) unsigned short us8;
typedef __attribute__((ext_vector_type(4))) float f32x4;

// --------------------------- bf16 split helpers -----------------------------
__device__ inline unsigned short bfh(float x) {
    unsigned u = __float_as_uint(x);
    unsigned r = (u + 0x7FFFu + ((u >> 16) & 1u)) >> 16;
    return (unsigned short)r;
}
__device__ inline float bfh_f(unsigned short h) {
    return __uint_as_float(((unsigned)h) << 16);
}
__device__ inline void bsplit(float x, unsigned short& h, unsigned short& l) {
    h = bfh(x);
    l = bfh(x - bfh_f(h));
}

// --------------------------- init -------------------------------------------
__global__ void k_init(const float* __restrict__ kappa, float* __restrict__ kap2,
                       float* __restrict__ dinv, float* __restrict__ x0,
                       float* __restrict__ acc) {
    int t = blockIdx.x * 256 + threadIdx.x;
    if (t < BB * NN) {
        float k = kappa[t];
        float k2 = k * k;
        kap2[t] = k2;
        dinv[t] = 1.0f / (4.0f * INVH2F - OMEGA2F * k2);
        x0[2 * t] = 0.f; x0[2 * t + 1] = 0.f;
    }
    if (t < 16) acc[t] = 0.f;
}

// --------------------------- transform matrices (fp32) ----------------------
__global__ void k_mats(float* __restrict__ S, float* __restrict__ W) {
    int t = blockIdx.x * 256 + threadIdx.x;
    if (t >= 257 * 257) return;
    int i = t / 257, j = t % 257;
    if (j < 256) {
        int a = (i - 128) * (j + 1);
        int m = ((a % 514) + 514) % 514;
        S[i * 256 + j] = sinf(m * TP514);
    }
    if (i < 256) {
        int tt = (i * (j + 129)) % 514;
        float cc = cosf(tt * TP514), ss = sinf(tt * TP514);
        float sg = (i & 1) ? -1.f : 1.f;
        W[(i * 257 + j) * 2] = sg * cc;
        W[(i * 257 + j) * 2 + 1] = -sg * ss;
    }
}

// --------------------------- static bf16 packs (KP=576 for W side) ----------
__global__ void k_packstat(const float* __restrict__ S, const float* __restrict__ W,
        unsigned short* sA1h, unsigned short* sA1l,
        unsigned short* sA2h, unsigned short* sA2l,
        unsigned short* wA1h, unsigned short* wA1l,
        unsigned short* wA2h, unsigned short* wA2l,
        unsigned short* wBh,  unsigned short* wBl) {
    int t = blockIdx.x * 256 + threadIdx.x;
    if (t >= 256 * 576) return;
    int i = t / 576, c = t % 576;
    {
        unsigned short h1 = 0, l1 = 0, h2 = 0, l2 = 0, hb = 0, lb = 0;
        if (c < 514) {
            int u = c >> 1;
            float wr = W[(i * 257 + u) * 2];
            float wi = W[(i * 257 + u) * 2 + 1];
            if ((c & 1) == 0) {
                bsplit(wr, h1, l1); bsplit(wi, h2, l2); bsplit(wr, hb, lb);
            } else {
                bsplit(-wi, h1, l1); bsplit(wr, h2, l2); bsplit(wi, hb, lb);
            }
        }
        size_t o = (size_t)i * 576 + c;
        wA1h[o] = h1; wA1l[o] = l1;
        wA2h[o] = h2; wA2l[o] = l2;
        wBh[o] = hb;  wBl[o] = lb;
    }
    if (i < 129 && c < 512) {
        int m = c >> 1;
        float s = S[i * 256 + m];
        unsigned short hs, ls;
        bsplit(s, hs, ls);
        size_t o = (size_t)i * 512 + c;
        if ((c & 1) == 0) { sA1h[o] = hs; sA1l[o] = ls; sA2h[o] = 0; sA2l[o] = 0; }
        else              { sA1h[o] = 0;  sA1l[o] = 0;  sA2h[o] = hs; sA2l[o] = ls; }
    }
}

// --------------------------- fused final residual + norm reduction ----------
__global__ void k_stepR(const float* __restrict__ xin,
                        const float* __restrict__ fr, const float* __restrict__ fi,
                        const float* __restrict__ kap2, float* __restrict__ acc) {
    int t = blockIdx.x * 256 + threadIdx.x;
    int b = t >> 16;
    int ij = t & 65535;
    int i = ij >> 8, j = ij & 255;
    const float* xb = xin + (size_t)b * NN * 2;
    float xcr = xb[2 * ij], xci = xb[2 * ij + 1];
    float ur, ui, dr, di, lr, li, rr, ri;
    if (i > 0) { int n = ij - 256; ur = xb[2 * n]; ui = xb[2 * n + 1]; }
    else { int n = 256 + j; ur = xb[2 * n] - BCVF * xci; ui = xb[2 * n + 1] + BCVF * xcr; }
    if (i < 255) { int n = ij + 256; dr = xb[2 * n]; di = xb[2 * n + 1]; }
    else { int n = 254 * 256 + j; dr = xb[2 * n] - BCVF * xci; di = xb[2 * n + 1] + BCVF * xcr; }
    if (j > 0) { int n = ij - 1; lr = xb[2 * n]; li = xb[2 * n + 1]; }
    else { int n = i * 256 + 1; lr = xb[2 * n] - BCVF * xci; li = xb[2 * n + 1] + BCVF * xcr; }
    if (j < 255) { int n = ij + 1; rr = xb[2 * n]; ri = xb[2 * n + 1]; }
    else { int n = i * 256 + 254; rr = xb[2 * n] - BCVF * xci; ri = xb[2 * n + 1] + BCVF * xcr; }
    float k2 = kap2[t];
    float axr = (4.f * xcr - ur - dr - lr - rr) * INVH2F - OMEGA2F * k2 * xcr;
    float axi = (4.f * xci - ui - di - li - ri) * INVH2F - OMEGA2F * k2 * xci;
    float fvr = fr[t], fvi = fi[t];
    float resr = fvr - axr, resi = fvi - axi;
    float sr = resr * resr + resi * resi;
    float sf = fvr * fvr + fvi * fvi;
    for (int off = 32; off > 0; off >>= 1) {
        sr += __shfl_down(sr, off);
        sf += __shfl_down(sf, off);
    }
    __shared__ float ssr[4], ssf[4];
    int tid = threadIdx.x;
    int wid = tid >> 6, lane = tid & 63;
    if (lane == 0) { ssr[wid] = sr; ssf[wid] = sf; }
    __syncthreads();
    if (tid == 0) {
        atomicAdd(&acc[2 * b], ssr[0] + ssr[1] + ssr[2] + ssr[3]);
        atomicAdd(&acc[2 * b + 1], ssf[0] + ssf[1] + ssf[2] + ssf[3]);
    }
}

// --------------------------- fused double stencil ---------------------------
template<int RESID>
__global__ __launch_bounds__(256) void k_step2(
        const float* __restrict__ xin, float* __restrict__ xout, float* __restrict__ rb,
        const float* __restrict__ fr, const float* __restrict__ fi,
        const float* __restrict__ kap2, const float* __restrict__ dinv) {
    const int b = blockIdx.y;
    const int tx = blockIdx.x & 7, ty = blockIdx.x >> 3;
    const int x0 = tx * 32, y0 = ty * 8;
    __shared__ float2 xs[12][37];
    __shared__ float2 ys[10][35];
    __shared__ float2 fs[10][35];
    __shared__ float ks2[10][35], ds2[10][35];
    const int tid = threadIdx.x;
    const float2* xb = (const float2*)xin + (size_t)b * NN;
    for (int i = tid; i < 432; i += 256) {
        int r = i / 36, c = i % 36;
        int gy = y0 - 2 + r, gx = x0 - 2 + c;
        float2 v = make_float2(0.f, 0.f);
        if ((unsigned)gy < 256u && (unsigned)gx < 256u) v = xb[gy * 256 + gx];
        xs[r][c] = v;
    }
    for (int i = tid; i < 340; i += 256) {
        int r = i / 34, c = i % 34;
        int gy = y0 - 1 + r, gx = x0 - 1 + c;
        float2 fv = make_float2(0.f, 0.f); float kv = 0.f, dvv = 0.f;
        if ((unsigned)gy < 256u && (unsigned)gx < 256u) {
            size_t o = (size_t)b * NN + gy * 256 + gx;
            fv = make_float2(fr[o], fi[o]); kv = kap2[o]; dvv = dinv[o];
        }
        fs[r][c] = fv; ks2[r][c] = kv; ds2[r][c] = dvv;
    }
    __syncthreads();
    for (int i = tid; i < 340; i += 256) {
        int r = i / 34, c = i % 34;
        int gy = y0 - 1 + r, gx = x0 - 1 + c;
        float2 o = make_float2(0.f, 0.f);
        if ((unsigned)gy < 256u && (unsigned)gx < 256u) {
            int xr = r + 1, xc = c + 1;
            float2 ctr = xs[xr][xc];
            float2 up, dn, lf, rt;
            if (gy > 0) up = xs[xr - 1][xc];
            else { float2 n = xs[xr + 1][xc]; up = make_float2(n.x - BCVF * ctr.y, n.y + BCVF * ctr.x); }
            if (gy < 255) dn = xs[xr + 1][xc];
            else { float2 n = xs[xr - 1][xc]; dn = make_float2(n.x - BCVF * ctr.y, n.y + BCVF * ctr.x); }
            if (gx > 0) lf = xs[xr][xc - 1];
            else { float2 n = xs[xr][xc + 1]; lf = make_float2(n.x - BCVF * ctr.y, n.y + BCVF * ctr.x); }
            if (gx < 255) rt = xs[xr][xc + 1];
            else { float2 n = xs[xr][xc - 1]; rt = make_float2(n.x - BCVF * ctr.y, n.y + BCVF * ctr.x); }
            float k2 = ks2[r][c];
            float axr = (4.f * ctr.x - up.x - dn.x - lf.x - rt.x) * INVH2F - OMEGA2F * k2 * ctr.x;
            float axi = (4.f * ctr.y - up.y - dn.y - lf.y - rt.y) * INVH2F - OMEGA2F * k2 * ctr.y;
            float2 fv = fs[r][c];
            float dv = ds2[r][c] * (2.0f / 3.0f);
            o = make_float2(ctr.x + dv * (fv.x - axr), ctr.y + dv * (fv.y - axi));
        }
        ys[r][c] = o;
    }
    __syncthreads();
    const int lx = tid & 31, ly = tid >> 5;
    const int gy = y0 + ly, gx = x0 + lx;
    const int yr = ly + 1, yc = lx + 1;
    float2 ctr = ys[yr][yc];
    float2 up, dn, lf, rt;
    if (gy > 0) up = ys[yr - 1][yc];
    else { float2 n = ys[yr + 1][yc]; up = make_float2(n.x - BCVF * ctr.y, n.y + BCVF * ctr.x); }
    if (gy < 255) dn = ys[yr + 1][yc];
    else { float2 n = ys[yr - 1][yc]; dn = make_float2(n.x - BCVF * ctr.y, n.y + BCVF * ctr.x); }
    if (gx > 0) lf = ys[yr][yc - 1];
    else { float2 n = ys[yr][yc + 1]; lf = make_float2(n.x - BCVF * ctr.y, n.y + BCVF * ctr.x); }
    if (gx < 255) rt = ys[yr][yc + 1];
    else { float2 n = ys[yr][yc - 1]; rt = make_float2(n.x - BCVF * ctr.y, n.y + BCVF * ctr.x); }
    float k2 = ks2[yr][yc];
    float axr = (4.f * ctr.x - up.x - dn.x - lf.x - rt.x) * INVH2F - OMEGA2F * k2 * ctr.x;
    float axi = (4.f * ctr.y - up.y - dn.y - lf.y - rt.y) * INVH2F - OMEGA2F * k2 * ctr.y;
    float2 fv = fs[yr][yc];
    size_t t = (size_t)b * NN + gy * 256 + gx;
    if (!RESID) {
        float dv = ds2[yr][yc] * (2.0f / 3.0f);
        xout[2 * t] = ctr.x + dv * (fv.x - axr);
        xout[2 * t + 1] = ctr.y + dv * (fv.y - axi);
    } else {
        xout[2 * t] = ctr.x; xout[2 * t + 1] = ctr.y;
        rb[2 * t] = fv.x - axr; rb[2 * t + 1] = fv.y - axi;
    }
}

// --------------------------- MFMA complex GEMM ------------------------------
// EPI: 0 store C, 1 add into C, 2 mirror-store (odd sym 257x257, scale),
//      3 write next-GEMM A-pack (P1/P2 h,l) instead of C.
// BGLO: stage B straight from fp32 cplx global (split in staging; no packT).
template<int EPI, int BGLO>
__global__ __launch_bounds__(256) void mgemm(
        const unsigned short* __restrict__ A1h, const unsigned short* __restrict__ A1l,
        const unsigned short* __restrict__ A2h, const unsigned short* __restrict__ A2l,
        const unsigned short* __restrict__ Bh,  const unsigned short* __restrict__ Bl,
        const float* __restrict__ Bgf, int ldbf, long bStrG, int bMin,
        float* __restrict__ C,
        unsigned short* __restrict__ P1h, unsigned short* __restrict__ P1l,
        unsigned short* __restrict__ P2h, unsigned short* __restrict__ P2l,
        int M, int N, int KP, int ldc, int KPout,
        long aStr, long bStr, long cStrF2, long pStr, float scale) {
    constexpr int LR = 72;
    __shared__ unsigned short shA1h[32 * LR], shA1l[32 * LR];
    __shared__ unsigned short shA2h[32 * LR], shA2l[32 * LR];
    __shared__ unsigned short shBh[32 * LR], shBl[32 * LR];
    const int tid = threadIdx.x;
    const int b = blockIdx.z;
    const unsigned short* pA1h = A1h + (size_t)b * aStr;
    const unsigned short* pA1l = A1l + (size_t)b * aStr;
    const unsigned short* pA2h = A2h + (size_t)b * aStr;
    const unsigned short* pA2l = A2l + (size_t)b * aStr;
    const int m0 = blockIdx.y * 32, n0 = blockIdx.x * 32;
    const int wave = tid >> 6, lane = tid & 63;
    const int wm = wave >> 1, wn = wave & 1;
    const int srow = tid >> 3, scol = (tid & 7) * 8;

    f32x4 accr = {0.f, 0.f, 0.f, 0.f}, acci = {0.f, 0.f, 0.f, 0.f};
    const int nks = KP >> 6;
    for (int ks = 0; ks < nks; ks++) {
        const int kb = ks * 64;
        const int so = srow * LR + scol;
        {
            int gm = m0 + srow;
            if (gm < M) {
                size_t ao = (size_t)gm * KP + kb + scol;
                *(us8*)&shA1h[so] = *(const us8*)&pA1h[ao];
                *(us8*)&shA1l[so] = *(const us8*)&pA1l[ao];
                *(us8*)&shA2h[so] = *(const us8*)&pA2h[ao];
                *(us8*)&shA2l[so] = *(const us8*)&pA2l[ao];
            } else {
                us8 z = (us8)0;
                *(us8*)&shA1h[so] = z; *(us8*)&shA1l[so] = z;
                *(us8*)&shA2h[so] = z; *(us8*)&shA2l[so] = z;
            }
        }
        if (BGLO) {
            int ul = tid >> 3;            // 0..31 local u (k' pair)
            int nl = (tid & 7) * 4;       // 0..28 local n
            int gu = (kb >> 1) + ul;
            const float2* bp = (const float2*)Bgf + (size_t)b * bStrG
                               + (size_t)gu * ldbf + (n0 + nl);
#pragma unroll
            for (int j = 0; j < 4; j++) {
                float2 v = make_float2(0.f, 0.f);
                if (gu < bMin && (n0 + nl + j) < N) v = bp[j];
                unsigned short h0, l0, h1, l1;
                bsplit(v.x, h0, l0); bsplit(v.y, h1, l1);
                int o = (nl + j) * LR + 2 * ul;
                shBh[o] = h0;     shBl[o] = l0;
                shBh[o + 1] = h1; shBl[o + 1] = l1;
            }
        } else {
            const unsigned short* pBh = Bh + (size_t)b * bStr;
            const unsigned short* pBl = Bl + (size_t)b * bStr;
            int gn = n0 + srow;
            if (gn < N) {
                size_t bo = (size_t)gn * KP + kb + scol;
                *(us8*)&shBh[so] = *(const us8*)&pBh[bo];
                *(us8*)&shBl[so] = *(const us8*)&pBl[bo];
            } else {
                us8 z = (us8)0;
                *(us8*)&shBh[so] = z; *(us8*)&shBl[so] = z;
            }
        }
        __syncthreads();
#pragma unroll
        for (int half = 0; half < 2; half++) {
            const int ko = half * 32 + ((lane >> 4) << 3);
            const int ar = (wm * 16 + (lane & 15)) * LR + ko;
            const int br = (wn * 16 + (lane & 15)) * LR + ko;
            short8v a1h = *(const short8v*)&shA1h[ar];
            short8v a1l = *(const short8v*)&shA1l[ar];
            short8v a2h = *(const short8v*)&shA2h[ar];
            short8v a2l = *(const short8v*)&shA2l[ar];
            short8v bh  = *(const short8v*)&shBh[br];
            short8v bl  = *(const short8v*)&shBl[br];
            accr = __builtin_amdgcn_mfma_f32_16x16x32_bf16(a1h, bh, accr, 0, 0, 0);
            accr = __builtin_amdgcn_mfma_f32_16x16x32_bf16(a1l, bh, accr, 0, 0, 0);
            accr = __builtin_amdgcn_mfma_f32_16x16x32_bf16(a1h, bl, accr, 0, 0, 0);
            acci = __builtin_amdgcn_mfma_f32_16x16x32_bf16(a2h, bh, acci, 0, 0, 0);
            acci = __builtin_amdgcn_mfma_f32_16x16x32_bf16(a2l, bh, acci, 0, 0, 0);
            acci = __builtin_amdgcn_mfma_f32_16x16x32_bf16(a2h, bl, acci, 0, 0, 0);
        }
        __syncthreads();
    }
    const int col = n0 + wn * 16 + (lane & 15);
    const int rbase = m0 + wm * 16 + ((lane >> 4) << 2);
    if (EPI == 3) {
        unsigned short* q1h = P1h + (size_t)b * pStr;
        unsigned short* q1l = P1l + (size_t)b * pStr;
        unsigned short* q2h = P2h + (size_t)b * pStr;
        unsigned short* q2l = P2l + (size_t)b * pStr;
#pragma unroll
        for (int i = 0; i < 4; i++) {
            int row = rbase + i;
            if (row >= M || col >= N) continue;
            float vr = scale * accr[i], vi = scale * acci[i];
            unsigned short hr, lr2, hi2, li2;
            bsplit(vr, hr, lr2); bsplit(vi, hi2, li2);
            size_t o = (size_t)row * KPout + 2 * col;
            q1h[o] = hr;  q1h[o + 1] = hi2 ^ 0x8000;
            q1l[o] = lr2; q1l[o + 1] = li2 ^ 0x8000;
            q2h[o] = hi2; q2h[o + 1] = hr;
            q2l[o] = li2; q2l[o + 1] = lr2;
        }
    } else {
        float* Cb = C + (size_t)b * cStrF2 * 2;
#pragma unroll
        for (int i = 0; i < 4; i++) {
            int row = rbase + i;
            if (row >= M || col >= N) continue;
            float vr = scale * accr[i], vi = scale * acci[i];
            if (EPI == 2) {
                int mm = 256 - row, nm = 256 - col;
                Cb[((size_t)row * 257 + col) * 2] = vr;  Cb[((size_t)row * 257 + col) * 2 + 1] = vi;
                Cb[((size_t)mm * 257 + col) * 2] = -vr;  Cb[((size_t)mm * 257 + col) * 2 + 1] = -vi;
                Cb[((size_t)row * 257 + nm) * 2] = -vr;  Cb[((size_t)row * 257 + nm) * 2 + 1] = -vi;
                Cb[((size_t)mm * 257 + nm) * 2] = vr;    Cb[((size_t)mm * 257 + nm) * 2 + 1] = vi;
            } else {
                size_t o = ((size_t)row * ldc + col) * 2;
                if (EPI == 1) { Cb[o] += vr; Cb[o + 1] += vi; }
                else          { Cb[o] = vr;  Cb[o + 1] = vi; }
            }
        }
    }
}

// --------------------------- fused 3-conv chain (+wt) - R7 body -------------
// ADJ=0: w1(1->4), w2(4->4), w3(4->1), then *wt (WTM).
// ADJ=1: w3^H(1->4), w2^H(4->4), w1^H(4->1).
// Channel-major grid-stride passes: 44 VGPR, 57 us (R7/R10 measured).
// DO NOT rewrite ch-inner/position-major: R8/R9/R13 all spilled (256 VGPR
// or scratch traffic). This body is load-redundant but allocator-friendly.
template<int ADJ, int WTM>
__global__ __launch_bounds__(256) void k_convChain(
        const float* __restrict__ in, float* __restrict__ out,
        const float* __restrict__ w1r, const float* __restrict__ w1i,
        const float* __restrict__ w2r, const float* __restrict__ w2i,
        const float* __restrict__ w3r, const float* __restrict__ w3i,
        const float* __restrict__ wtr, const float* __restrict__ wti) {
    const int b = blockIdx.y;
    const int bx = blockIdx.x % 9, by = blockIdx.x / 9;
    const int x0 = bx * 32, y0 = by * 8;
    __shared__ float2 sh0[14][39];
    __shared__ float2 i1[4][12][37];
    __shared__ float2 i2[4][10][35];
    __shared__ float wAr[36], wAi[36], wBr[144], wBi[144], wCr[36], wCi[36];
    const int tid = threadIdx.x;
    if (tid < 36) {
        int o = tid / 9, pq = tid % 9, p = pq / 3, q = pq % 3;
        if (!ADJ) { int idx = b * 36 + o * 9 + pq; wAr[tid] = w1r[idx]; wAi[tid] = w1i[idx]; }
        else      { int idx = b * 36 + o * 9 + q * 3 + p; wAr[tid] = w3r[idx]; wAi[tid] = -w3i[idx]; }
    } else if (tid < 180) {
        int j = tid - 36; int o = j / 36, ci = (j / 9) & 3, pq = j % 9, p = pq / 3, q = pq % 3;
        if (!ADJ) { int idx = b * 144 + (o * 4 + ci) * 9 + pq; wBr[j] = w2r[idx]; wBi[j] = w2i[idx]; }
        else      { int idx = b * 144 + (ci * 4 + o) * 9 + q * 3 + p; wBr[j] = w2r[idx]; wBi[j] = -w2i[idx]; }
    } else if (tid < 216) {
        int j = tid - 180; int ci = j / 9, pq = j % 9, p = pq / 3, q = pq % 3;
        if (!ADJ) { int idx = b * 36 + ci * 9 + pq; wCr[j] = w3r[idx]; wCi[j] = w3i[idx]; }
        else      { int idx = b * 36 + ci * 9 + q * 3 + p; wCr[j] = w1r[idx]; wCi[j] = -w1i[idx]; }
    }
    const float2* ipb = (const float2*)in + (size_t)b * MM;
    for (int i = tid; i < 14 * 38; i += 256) {
        int r = i / 38, c = i % 38;
        int gy = y0 - 3 + r, gx = x0 - 3 + c;
        float2 v = make_float2(0.f, 0.f);
        if ((unsigned)gy < 257u && (unsigned)gx < 257u) v = ipb[(size_t)gy * 257 + gx];
        sh0[r][c] = v;
    }
    __syncthreads();
    for (int i = tid; i < 1728; i += 256) {
        int ch = i / 432, rem = i % 432, r = rem / 36, c = rem % 36;
        int gy = y0 - 2 + r, gx = x0 - 2 + c;
        float ar = 0.f, ai = 0.f;
        if ((unsigned)gy < 257u && (unsigned)gx < 257u) {
#pragma unroll
            for (int p = 0; p < 3; p++)
#pragma unroll
                for (int q = 0; q < 3; q++) {
                    float2 v = sh0[r + p][c + q];
                    float wr = wAr[ch * 9 + p * 3 + q], wi = wAi[ch * 9 + p * 3 + q];
                    ar += v.x * wr - v.y * wi;
                    ai += v.x * wi + v.y * wr;
                }
        }
        i1[ch][r][c] = make_float2(ar, ai);
    }
    __syncthreads();
    for (int i = tid; i < 1360; i += 256) {
        int ch = i / 340, rem = i % 340, r = rem / 34, c = rem % 34;
        int gy = y0 - 1 + r, gx = x0 - 1 + c;
        float ar = 0.f, ai = 0.f;
        if ((unsigned)gy < 257u && (unsigned)gx < 257u) {
#pragma unroll
            for (int ci = 0; ci < 4; ci++)
#pragma unroll
                for (int p = 0; p < 3; p++)
#pragma unroll
                    for (int q = 0; q < 3; q++) {
                        float2 v = i1[ci][r + p][c + q];
                        float wr = wBr[(ch * 4 + ci) * 9 + p * 3 + q];
                        float wi = wBi[(ch * 4 + ci) * 9 + p * 3 + q];
                        ar += v.x * wr - v.y * wi;
                        ai += v.x * wi + v.y * wr;
                    }
        }
        i2[ch][r][c] = make_float2(ar, ai);
    }
    __syncthreads();
    const int lx = tid & 31, ly = tid >> 5;
    const int x = x0 + lx, y = y0 + ly;
    if (x >= 257 || y >= 257) return;
    float ar = 0.f, ai = 0.f;
#pragma unroll
    for (int ci = 0; ci < 4; ci++)
#pragma unroll
        for (int p = 0; p < 3; p++)
#pragma unroll
            for (int q = 0; q < 3; q++) {
                float2 v = i2[ci][ly + p][lx + q];
                float wr = wCr[ci * 9 + p * 3 + q], wi = wCi[ci * 9 + p * 3 + q];
                ar += v.x * wr - v.y * wi;
                ai += v.x * wi + v.y * wr;
            }
    if (WTM) {
        size_t wo = (size_t)b * MM + (size_t)y * 257 + x;
        float wr = wtr[wo], wi = wti[wo];
        float r0 = ar * wr - ai * wi;
        float i0 = ar * wi + ai * wr;
        ar = r0; ai = i0;
    }
    ((float2*)out)[(size_t)b * MM + (size_t)y * 257 + x] = make_float2(ar, ai);
}

__global__ void k_finalize(const float* __restrict__ acc, float* __restrict__ out) {
    if (threadIdx.x == 0 && blockIdx.x == 0) {
        float num = 0.f, den = 0.f;
        for (int b = 0; b < BB; b++) {
            num += sqrtf(acc[2 * b]);
            den += sqrtf(acc[2 * b + 1]);
        }
        out[0] = num / den;
    }
}

// ---------------------------------------------------------------------------
extern "C" void kernel_launch(void* const* d_in, const int* in_sizes, int n_in,
                              void* d_out, int out_size, void* d_ws, size_t ws_size,
                              hipStream_t stream) {
    (void)in_sizes; (void)n_in; (void)out_size; (void)ws_size;
    const float* fr  = (const float*)d_in[0];
    const float* fi  = (const float*)d_in[1];
    const float* kap = (const float*)d_in[2];
    const float* w1r = (const float*)d_in[3];
    const float* w1i = (const float*)d_in[4];
    const float* w2r = (const float*)d_in[5];
    const float* w2i = (const float*)d_in[6];
    const float* w3r = (const float*)d_in[7];
    const float* w3i = (const float*)d_in[8];
    const float* wtr = (const float*)d_in[9];
    const float* wti = (const float*)d_in[10];
    const int K = 3;   // epoch=81 -> (81-1)/40+1

    float* ws = (float*)d_ws;
    size_t off = 0;
    float* x0   = ws + off; off += (size_t)BB * NN * 2;
    float* x1   = ws + off; off += (size_t)BB * NN * 2;
    float* x2   = ws + off; off += (size_t)BB * NN * 2;
    float* rb   = ws + off; off += (size_t)BB * NN * 2;
    float* kap2 = ws + off; off += (size_t)BB * NN;
    float* dinv = ws + off; off += (size_t)BB * NN;
    float* tA   = ws + off; off += (size_t)BB * MM * 2;
    float* tB   = ws + off; off += (size_t)BB * MM * 2;
    float* u1   = ws + off; off += (size_t)BB * MM * 2;
    float* S    = ws + off; off += 257 * 256;
    float* W    = ws + off; off += 256 * 257 * 2;
    float* acc  = ws + off; off += 16;

    unsigned short* us = (unsigned short*)(ws + off);
    size_t so = 0;
    unsigned short* sA1h = us + so; so += 129 * 512;
    unsigned short* sA1l = us + so; so += 129 * 512;
    unsigned short* sA2h = us + so; so += 129 * 512;
    unsigned short* sA2l = us + so; so += 129 * 512;
    unsigned short* wA1h = us + so; so += 256 * 576;
    unsigned short* wA1l = us + so; so += 256 * 576;
    unsigned short* wA2h = us + so; so += 256 * 576;
    unsigned short* wA2l = us + so; so += 256 * 576;
    unsigned short* wBh  = us + so; so += 256 * 576;
    unsigned short* wBl  = us + so; so += 256 * 576;
    const long DSASTR = (long)129 * 512;
    unsigned short* dsA1h = us + so; so += (size_t)BB * DSASTR;
    unsigned short* dsA1l = us + so; so += (size_t)BB * DSASTR;
    unsigned short* dsA2h = us + so; so += (size_t)BB * DSASTR;
    unsigned short* dsA2l = us + so; so += (size_t)BB * DSASTR;
    const long DFASTR = (long)256 * 576;
    unsigned short* dfA1h = us + so; so += (size_t)BB * DFASTR;
    unsigned short* dfA1l = us + so; so += (size_t)BB * DFASTR;
    unsigned short* dfA2h = us + so; so += (size_t)BB * DFASTR;
    unsigned short* dfA2l = us + so; so += (size_t)BB * DFASTR;

    int sgrid = (BB * NN + 255) / 256;
    k_init<<<sgrid, 256, 0, stream>>>(kap, kap2, dinv, x0, acc);
    k_mats<<<(257 * 257 + 255) / 256, 256, 0, stream>>>(S, W);
    k_packstat<<<(256 * 576 + 255) / 256, 256, 0, stream>>>(
        S, W, sA1h, sA1l, sA2h, sA2l, wA1h, wA1l, wA2h, wA2l, wBh, wBl);

    float* xc = x0;
    for (int it = 0; it < K; ++it) {
        float* xn = (xc == x0) ? x2 : x0;
        k_step2<0><<<dim3(256, BB), 256, 0, stream>>>(xc, x1, rb, fr, fi, kap2, dinv);
        k_step2<1><<<dim3(256, BB), 256, 0, stream>>>(x1, xn, rb, fr, fi, kap2, dinv);

        // DST1: T[u<129][p<256] = S * rb  (B = rb fp32 direct) -> dsA pack
        mgemm<3, 1><<<dim3(8, 5, BB), 256, 0, stream>>>(
            sA1h, sA1l, sA2h, sA2l, nullptr, nullptr,
            rb, 256, (long)NN, 256,
            nullptr, dsA1h, dsA1l, dsA2h, dsA2l,
            129, 256, 512, 0, 512,
            0, 0, 0, DSASTR, 1.f);
        // DST2 quadrant + mirror -> tB (257x257)
        mgemm<2, 0><<<dim3(5, 5, BB), 256, 0, stream>>>(
            dsA1h, dsA1l, dsA2h, dsA2l, sA1h, sA1l,
            nullptr, 0, 0, 0,
            tB, nullptr, nullptr, nullptr, nullptr,
            129, 129, 512, 257, 0,
            DSASTR, 0, (long)MM, 0, C1F);

        // conv chains (forward +wt, adjoint)
        k_convChain<0, 1><<<dim3(297, BB), 256, 0, stream>>>(
            tB, u1, w1r, w1i, w2r, w2i, w3r, w3i, wtr, wti);
        k_convChain<1, 0><<<dim3(297, BB), 256, 0, stream>>>(
            u1, tA, w1r, w1i, w2r, w2i, w3r, w3i, wtr, wti);

        // DFT1: G[k<256][v<257] = W * tA  (B = tA fp32 direct) -> dfA pack
        mgemm<3, 1><<<dim3(9, 8, BB), 256, 0, stream>>>(
            wA1h, wA1l, wA2h, wA2l, nullptr, nullptr,
            tA, 257, (long)MM, 257,
            nullptr, dfA1h, dfA1l, dfA2h, dfA2l,
            256, 257, 576, 0, 576,
            0, 0, 0, DFASTR, 1.f);
        // DFT2 + add into xn
        mgemm<1, 0><<<dim3(8, 8, BB), 256, 0, stream>>>(
            dfA1h, dfA1l, dfA2h, dfA2l, wBh, wBl,
            nullptr, 0, 0, 0,
            xn, nullptr, nullptr, nullptr, nullptr,
            256, 256, 576, 256, 0,
            DFASTR, 0, (long)NN, 0, 1.f);
        xc = xn;
    }
    k_stepR<<<sgrid, 256, 0, stream>>>(xc, fr, fi, kap2, acc);
    k_finalize<<<1, 64, 0, stream>>>(acc, (float*)d_out);
}